// Round 1
// baseline (3177.166 us; speedup 1.0000x reference)
//
#include <hip/hip_runtime.h>

#define D 128
#define G_NUM 512
#define TILE_M 64
#define BK 16

// ---------------- degree + per-graph count ----------------
__global__ void deg_cnt_kernel(const int* __restrict__ tgt, const int* __restrict__ batch,
                               float* __restrict__ deg, float* __restrict__ cnt,
                               int E, int N) {
    int id = blockIdx.x * blockDim.x + threadIdx.x;
    if (id < E) {
        atomicAdd(&deg[tgt[id]], 1.0f);
    } else if (id < E + N) {
        atomicAdd(&cnt[batch[id - E]], 1.0f);
    }
}

__global__ void recip_kernel(float* __restrict__ deg, int N) {
    int i = blockIdx.x * blockDim.x + threadIdx.x;
    if (i < N) deg[i] = 1.0f / fmaxf(deg[i], 1.0f);
}

// ---------------- edge scatter-add: agg[tgt] += feat[src] ----------------
// 32 threads per edge, float4 per thread (128 floats/edge).
__global__ void scatter_kernel(const int* __restrict__ src, const int* __restrict__ tgt,
                               const float* __restrict__ feat, float* __restrict__ agg, int E) {
    int id = blockIdx.x * blockDim.x + threadIdx.x;
    if (id >= E * 32) return;
    int e = id >> 5, q = id & 31;
    int s = src[e], t = tgt[e];
    float4 v = ((const float4*)feat)[s * 32 + q];
    float* dst = agg + (size_t)t * D + (q << 2);
    atomicAdd(dst + 0, v.x);
    atomicAdd(dst + 1, v.y);
    atomicAdd(dst + 2, v.z);
    atomicAdd(dst + 3, v.w);
}

// ---------------- fused SAGE GEMM: out = (agg*rdeg)@Wn + X@Wr + b ----------------
// 64 rows x 128 cols per block, 256 threads, 4x8 micro-tile per thread.
// RELU: apply relu (layer 1). POOL: atomically accumulate rows into pooled[batch[r]].
template <int RELU, int POOL>
__global__ __launch_bounds__(256) void sage_gemm_kernel(
    const float* __restrict__ A,     // agg [N][D]
    const float* __restrict__ rdeg,  // [N] 1/max(deg,1)
    const float* __restrict__ X,     // [N][D]
    const float* __restrict__ Wn,    // [D][D]
    const float* __restrict__ Wr,    // [D][D]
    const float* __restrict__ bias,  // [D]
    float* __restrict__ out,         // h1 [N][D]  or pooled [G][D]
    const int* __restrict__ batch,   // [N] (POOL only)
    int N) {
    __shared__ float As1[BK][68];   // [k][row], padded
    __shared__ float As2[BK][68];
    __shared__ float Bs1[BK][132];  // [k][col], padded
    __shared__ float Bs2[BK][132];

    int tid = threadIdx.x;
    int ty = tid >> 4, tx = tid & 15;
    int m0 = blockIdx.x * TILE_M;

    // staging mapping for A tiles: each thread loads one float4 per matrix
    int arow = tid >> 2;              // 0..63
    int ak = (tid & 3) << 2;          // 0,4,8,12
    int ga = min(m0 + arow, N - 1);
    float rd = rdeg[ga];
    const float4* Arow = (const float4*)(A + (size_t)ga * D);
    const float4* Xrow = (const float4*)(X + (size_t)ga * D);

    float acc[4][8];
#pragma unroll
    for (int i = 0; i < 4; i++)
#pragma unroll
        for (int j = 0; j < 8; j++) acc[i][j] = 0.f;

    for (int k0 = 0; k0 < D; k0 += BK) {
        float4 va = Arow[(k0 + ak) >> 2];
        float4 vx = Xrow[(k0 + ak) >> 2];
        As1[ak + 0][arow] = va.x * rd;
        As1[ak + 1][arow] = va.y * rd;
        As1[ak + 2][arow] = va.z * rd;
        As1[ak + 3][arow] = va.w * rd;
        As2[ak + 0][arow] = vx.x;
        As2[ak + 1][arow] = vx.y;
        As2[ak + 2][arow] = vx.z;
        As2[ak + 3][arow] = vx.w;
#pragma unroll
        for (int r = 0; r < 2; r++) {
            int idx = tid + r * 256;
            int kk = idx >> 5, c4 = (idx & 31) << 2;
            float4 wn = *(const float4*)(Wn + (size_t)(k0 + kk) * D + c4);
            float4 wr = *(const float4*)(Wr + (size_t)(k0 + kk) * D + c4);
            *(float4*)&Bs1[kk][c4] = wn;
            *(float4*)&Bs2[kk][c4] = wr;
        }
        __syncthreads();
#pragma unroll
        for (int kk = 0; kk < BK; kk++) {
            float a1[4], a2[4], b1[8], b2[8];
            *(float4*)a1 = *(const float4*)&As1[kk][ty << 2];
            *(float4*)a2 = *(const float4*)&As2[kk][ty << 2];
            *(float4*)&b1[0] = *(const float4*)&Bs1[kk][tx << 2];
            *(float4*)&b1[4] = *(const float4*)&Bs1[kk][64 + (tx << 2)];
            *(float4*)&b2[0] = *(const float4*)&Bs2[kk][tx << 2];
            *(float4*)&b2[4] = *(const float4*)&Bs2[kk][64 + (tx << 2)];
#pragma unroll
            for (int i = 0; i < 4; i++)
#pragma unroll
                for (int j = 0; j < 8; j++)
                    acc[i][j] += a1[i] * b1[j] + a2[i] * b2[j];
        }
        __syncthreads();
    }

#pragma unroll
    for (int i = 0; i < 4; i++) {
        int r = m0 + (ty << 2) + i;
        if (r >= N) continue;
        int bidx = POOL ? batch[r] : 0;
#pragma unroll
        for (int jg = 0; jg < 2; jg++) {
            int c0 = jg * 64 + (tx << 2);
            float4 v;
            v.x = acc[i][jg * 4 + 0] + bias[c0 + 0];
            v.y = acc[i][jg * 4 + 1] + bias[c0 + 1];
            v.z = acc[i][jg * 4 + 2] + bias[c0 + 2];
            v.w = acc[i][jg * 4 + 3] + bias[c0 + 3];
            if (RELU) {
                v.x = fmaxf(v.x, 0.f);
                v.y = fmaxf(v.y, 0.f);
                v.z = fmaxf(v.z, 0.f);
                v.w = fmaxf(v.w, 0.f);
            }
            if (POOL) {
                float* dst = out + (size_t)bidx * D + c0;
                atomicAdd(dst + 0, v.x);
                atomicAdd(dst + 1, v.y);
                atomicAdd(dst + 2, v.z);
                atomicAdd(dst + 3, v.w);
            } else {
                *(float4*)(out + (size_t)r * D + c0) = v;
            }
        }
    }
}

// ---------------- final: out[g] = (pooled[g]/cnt[g]) @ fc_w + fc_b ----------------
__global__ void final_kernel(const float* __restrict__ pooled, const float* __restrict__ cnt,
                             const float* __restrict__ fcw, const float* __restrict__ fcb,
                             float* __restrict__ out) {
    __shared__ float p[D];
    int g = blockIdx.x, t = threadIdx.x;
    float rc = 1.0f / fmaxf(cnt[g], 1.0f);
    p[t] = pooled[g * D + t] * rc;
    __syncthreads();
    if (t < 10) {
        float acc = fcb[t];
#pragma unroll
        for (int k = 0; k < D; k++) acc += p[k] * fcw[k * 10 + t];
        out[g * 10 + t] = acc;
    }
}

extern "C" void kernel_launch(void* const* d_in, const int* in_sizes, int n_in,
                              void* d_out, int out_size, void* d_ws, size_t ws_size,
                              hipStream_t stream) {
    const float* x   = (const float*)d_in[0];
    const int*   ei  = (const int*)d_in[1];
    const int* batch = (const int*)d_in[2];
    const float* w1n = (const float*)d_in[3];
    const float* b1  = (const float*)d_in[4];
    const float* w1r = (const float*)d_in[5];
    const float* w2n = (const float*)d_in[6];
    const float* b2  = (const float*)d_in[7];
    const float* w2r = (const float*)d_in[8];
    const float* fcw = (const float*)d_in[9];
    const float* fcb = (const float*)d_in[10];
    float* out = (float*)d_out;

    int N = in_sizes[0] / D;
    int E = in_sizes[1] / 2;
    const int* src = ei;
    const int* tgt = ei + E;

    float* ws = (float*)d_ws;
    float* deg    = ws;                                // N
    float* cnt    = deg + N;                           // G_NUM
    float* pooled = cnt + G_NUM;                       // G_NUM*D
    float* agg    = pooled + (size_t)G_NUM * D;        // N*D
    float* h1     = agg + (size_t)N * D;               // N*D

    // zero deg, cnt, pooled, agg in one contiguous memset
    size_t zero1 = ((size_t)N + G_NUM + (size_t)G_NUM * D + (size_t)N * D) * sizeof(float);
    hipMemsetAsync(d_ws, 0, zero1, stream);

    int tot = E + N;
    deg_cnt_kernel<<<(tot + 255) / 256, 256, 0, stream>>>(tgt, batch, deg, cnt, E, N);
    recip_kernel<<<(N + 255) / 256, 256, 0, stream>>>(deg, N);

    int sthreads = E * 32;
    scatter_kernel<<<(sthreads + 255) / 256, 256, 0, stream>>>(src, tgt, x, agg, E);

    int gblocks = (N + TILE_M - 1) / TILE_M;
    sage_gemm_kernel<1, 0><<<gblocks, 256, 0, stream>>>(agg, deg, x, w1n, w1r, b1, h1, nullptr, N);

    hipMemsetAsync(agg, 0, (size_t)N * D * sizeof(float), stream);
    scatter_kernel<<<(sthreads + 255) / 256, 256, 0, stream>>>(src, tgt, h1, agg, E);
    sage_gemm_kernel<0, 1><<<gblocks, 256, 0, stream>>>(agg, deg, h1, w2n, w2r, b2, pooled, batch, N);

    final_kernel<<<G_NUM, D, 0, stream>>>(pooled, cnt, fcw, fcb, out);
}

// Round 2
// 821.695 us; speedup vs baseline: 3.8666x; 3.8666x over previous
//
#include <hip/hip_runtime.h>

#define D 128
#define G_NUM 512
#define TILE_M 64
#define BK 16

// ---------------- in-degree histogram + per-graph count ----------------
__global__ void deg_cnt_kernel(const int* __restrict__ tgt, const int* __restrict__ batch,
                               int* __restrict__ deg, float* __restrict__ cnt,
                               int E, int N) {
    int id = blockIdx.x * blockDim.x + threadIdx.x;
    if (id < E) {
        atomicAdd(&deg[tgt[id]], 1);
    } else if (id < E + N) {
        atomicAdd(&cnt[batch[id - E]], 1.0f);
    }
}

// ---------------- block-level exclusive scan (step 1) ----------------
__global__ void scan1_kernel(const int* __restrict__ deg, int* __restrict__ row_excl,
                             int* __restrict__ partial, int N) {
    __shared__ int s[256];
    int t = threadIdx.x, i = blockIdx.x * 256 + t;
    int v = (i < N) ? deg[i] : 0;
    s[t] = v;
    __syncthreads();
    for (int off = 1; off < 256; off <<= 1) {
        int add = (t >= off) ? s[t - off] : 0;
        __syncthreads();
        s[t] += add;
        __syncthreads();
    }
    if (i < N) row_excl[i] = s[t] - v;   // exclusive within block
    if (t == 255) partial[blockIdx.x] = s[255];
}

// ---------------- scan block sums (step 2, NB <= 256) ----------------
__global__ void scan2_kernel(int* __restrict__ partial, int NB) {
    __shared__ int s[256];
    int t = threadIdx.x;
    int v = (t < NB) ? partial[t] : 0;
    s[t] = v;
    __syncthreads();
    for (int off = 1; off < 256; off <<= 1) {
        int add = (t >= off) ? s[t - off] : 0;
        __syncthreads();
        s[t] += add;
        __syncthreads();
    }
    if (t < NB) partial[t] = s[t] - v;   // exclusive block offsets
}

// ---------------- add offsets (step 3) + rdeg + reset cursor ----------------
__global__ void scan3_kernel(int* __restrict__ row_start, const int* __restrict__ partial,
                             int* __restrict__ deg, float* __restrict__ rdeg, int N, int E) {
    int i = blockIdx.x * blockDim.x + threadIdx.x;
    if (i < N) {
        row_start[i] += partial[blockIdx.x * 256 / 256];  // one block = 256 elems
        float d = (float)deg[i];
        rdeg[i] = 1.0f / fmaxf(d, 1.0f);
        deg[i] = 0;  // becomes fill cursor
    }
    if (i == 0) row_start[N] = E;
}

// ---------------- CSR fill ----------------
__global__ void fill_kernel(const int* __restrict__ src, const int* __restrict__ tgt,
                            const int* __restrict__ row_start, int* __restrict__ cursor,
                            int* __restrict__ col_idx, int E) {
    int e = blockIdx.x * blockDim.x + threadIdx.x;
    if (e >= E) return;
    int t = tgt[e];
    int pos = row_start[t] + atomicAdd(&cursor[t], 1);
    col_idx[pos] = src[e];
}

// ---------------- atomic-free gather aggregation: agg[n] = mean_{s in N(n)} feat[s] ----------------
// 2 nodes per 256-thread block; 128 threads per node (one feature column each).
__global__ __launch_bounds__(256) void gather_agg_kernel(
    const int* __restrict__ row_start, const int* __restrict__ col_idx,
    const float* __restrict__ rdeg, const float* __restrict__ feat,
    float* __restrict__ agg, int N) {
    int node = blockIdx.x * 2 + (threadIdx.x >> 7);
    if (node >= N) return;
    int t = threadIdx.x & 127;
    int beg = row_start[node], end = row_start[node + 1];
    float acc = 0.f;
    for (int i = beg; i < end; i++) {
        int s = col_idx[i];  // wave-uniform broadcast load
        acc += feat[(size_t)s * D + t];
    }
    agg[(size_t)node * D + t] = acc * rdeg[node];
}

// ---------------- fused SAGE GEMM: out = Agg@Wn + X@Wr + b ----------------
// 64 rows x 128 cols per block, 256 threads, 4x8 micro-tile per thread.
template <int RELU, int POOL>
__global__ __launch_bounds__(256) void sage_gemm_kernel(
    const float* __restrict__ A,     // agg [N][D] (pre-normalized)
    const float* __restrict__ X,     // [N][D]
    const float* __restrict__ Wn,    // [D][D]
    const float* __restrict__ Wr,    // [D][D]
    const float* __restrict__ bias,  // [D]
    float* __restrict__ out,         // h1 [N][D]  or pooled [G][D]
    const int* __restrict__ batch,   // [N] (POOL only)
    int N) {
    __shared__ float As1[BK][68];   // [k][row], padded
    __shared__ float As2[BK][68];
    __shared__ float Bs1[BK][132];  // [k][col], padded
    __shared__ float Bs2[BK][132];

    int tid = threadIdx.x;
    int ty = tid >> 4, tx = tid & 15;
    int m0 = blockIdx.x * TILE_M;

    int arow = tid >> 2;              // 0..63
    int ak = (tid & 3) << 2;          // 0,4,8,12
    int ga = min(m0 + arow, N - 1);
    const float4* Arow = (const float4*)(A + (size_t)ga * D);
    const float4* Xrow = (const float4*)(X + (size_t)ga * D);

    float acc[4][8];
#pragma unroll
    for (int i = 0; i < 4; i++)
#pragma unroll
        for (int j = 0; j < 8; j++) acc[i][j] = 0.f;

    for (int k0 = 0; k0 < D; k0 += BK) {
        float4 va = Arow[(k0 + ak) >> 2];
        float4 vx = Xrow[(k0 + ak) >> 2];
        As1[ak + 0][arow] = va.x;
        As1[ak + 1][arow] = va.y;
        As1[ak + 2][arow] = va.z;
        As1[ak + 3][arow] = va.w;
        As2[ak + 0][arow] = vx.x;
        As2[ak + 1][arow] = vx.y;
        As2[ak + 2][arow] = vx.z;
        As2[ak + 3][arow] = vx.w;
#pragma unroll
        for (int r = 0; r < 2; r++) {
            int idx = tid + r * 256;
            int kk = idx >> 5, c4 = (idx & 31) << 2;
            float4 wn = *(const float4*)(Wn + (size_t)(k0 + kk) * D + c4);
            float4 wr = *(const float4*)(Wr + (size_t)(k0 + kk) * D + c4);
            *(float4*)&Bs1[kk][c4] = wn;
            *(float4*)&Bs2[kk][c4] = wr;
        }
        __syncthreads();
#pragma unroll
        for (int kk = 0; kk < BK; kk++) {
            float a1[4], a2[4], b1[8], b2[8];
            *(float4*)a1 = *(const float4*)&As1[kk][ty << 2];
            *(float4*)a2 = *(const float4*)&As2[kk][ty << 2];
            *(float4*)&b1[0] = *(const float4*)&Bs1[kk][tx << 2];
            *(float4*)&b1[4] = *(const float4*)&Bs1[kk][64 + (tx << 2)];
            *(float4*)&b2[0] = *(const float4*)&Bs2[kk][tx << 2];
            *(float4*)&b2[4] = *(const float4*)&Bs2[kk][64 + (tx << 2)];
#pragma unroll
            for (int i = 0; i < 4; i++)
#pragma unroll
                for (int j = 0; j < 8; j++)
                    acc[i][j] += a1[i] * b1[j] + a2[i] * b2[j];
        }
        __syncthreads();
    }

#pragma unroll
    for (int i = 0; i < 4; i++) {
        int r = m0 + (ty << 2) + i;
        if (r >= N) continue;
        int bidx = POOL ? batch[r] : 0;
#pragma unroll
        for (int jg = 0; jg < 2; jg++) {
            int c0 = jg * 64 + (tx << 2);
            float4 v;
            v.x = acc[i][jg * 4 + 0] + bias[c0 + 0];
            v.y = acc[i][jg * 4 + 1] + bias[c0 + 1];
            v.z = acc[i][jg * 4 + 2] + bias[c0 + 2];
            v.w = acc[i][jg * 4 + 3] + bias[c0 + 3];
            if (RELU) {
                v.x = fmaxf(v.x, 0.f);
                v.y = fmaxf(v.y, 0.f);
                v.z = fmaxf(v.z, 0.f);
                v.w = fmaxf(v.w, 0.f);
            }
            if (POOL) {
                float* dst = out + (size_t)bidx * D + c0;
                atomicAdd(dst + 0, v.x);
                atomicAdd(dst + 1, v.y);
                atomicAdd(dst + 2, v.z);
                atomicAdd(dst + 3, v.w);
            } else {
                *(float4*)(out + (size_t)r * D + c0) = v;
            }
        }
    }
}

// ---------------- final: out[g] = (pooled[g]/cnt[g]) @ fc_w + fc_b ----------------
__global__ void final_kernel(const float* __restrict__ pooled, const float* __restrict__ cnt,
                             const float* __restrict__ fcw, const float* __restrict__ fcb,
                             float* __restrict__ out) {
    __shared__ float p[D];
    int g = blockIdx.x, t = threadIdx.x;
    float rc = 1.0f / fmaxf(cnt[g], 1.0f);
    p[t] = pooled[g * D + t] * rc;
    __syncthreads();
    if (t < 10) {
        float acc = fcb[t];
#pragma unroll
        for (int k = 0; k < D; k++) acc += p[k] * fcw[k * 10 + t];
        out[g * 10 + t] = acc;
    }
}

extern "C" void kernel_launch(void* const* d_in, const int* in_sizes, int n_in,
                              void* d_out, int out_size, void* d_ws, size_t ws_size,
                              hipStream_t stream) {
    const float* x   = (const float*)d_in[0];
    const int*   ei  = (const int*)d_in[1];
    const int* batch = (const int*)d_in[2];
    const float* w1n = (const float*)d_in[3];
    const float* b1  = (const float*)d_in[4];
    const float* w1r = (const float*)d_in[5];
    const float* w2n = (const float*)d_in[6];
    const float* b2  = (const float*)d_in[7];
    const float* w2r = (const float*)d_in[8];
    const float* fcw = (const float*)d_in[9];
    const float* fcb = (const float*)d_in[10];
    float* out = (float*)d_out;

    int N = in_sizes[0] / D;
    int E = in_sizes[1] / 2;
    const int* src = ei;
    const int* tgt = ei + E;
    int NB = (N + 255) / 256;

    // ---- workspace layout ----
    char* p = (char*)d_ws;
    int*   deg       = (int*)p;                 p += (size_t)N * 4;          // also fill-cursor
    float* cnt       = (float*)p;               p += (size_t)G_NUM * 4;
    float* pooled    = (float*)p;               p += (size_t)G_NUM * D * 4;
    int*   row_start = (int*)p;                 p += (size_t)(N + 1) * 4;
    int*   partial   = (int*)p;                 p += 256 * 4;
    int*   col_idx   = (int*)p;                 p += (size_t)E * 4;
    float* rdeg      = (float*)p;               p += (size_t)N * 4;
    float* agg       = (float*)p;               p += (size_t)N * D * 4;
    float* h1        = (float*)p;               p += (size_t)N * D * 4;

    // zero deg + cnt + pooled (contiguous prefix)
    size_t zbytes = ((size_t)N + G_NUM + (size_t)G_NUM * D) * 4;
    hipMemsetAsync(d_ws, 0, zbytes, stream);

    // ---- CSR build (once, reused by both layers) ----
    int tot = E + N;
    deg_cnt_kernel<<<(tot + 255) / 256, 256, 0, stream>>>(tgt, batch, deg, cnt, E, N);
    scan1_kernel<<<NB, 256, 0, stream>>>(deg, row_start, partial, N);
    scan2_kernel<<<1, 256, 0, stream>>>(partial, NB);
    scan3_kernel<<<NB, 256, 0, stream>>>(row_start, partial, deg, rdeg, N, E);
    fill_kernel<<<(E + 255) / 256, 256, 0, stream>>>(src, tgt, row_start, deg, col_idx, E);

    // ---- layer 1 ----
    int ablocks = (N + 1) / 2;
    gather_agg_kernel<<<ablocks, 256, 0, stream>>>(row_start, col_idx, rdeg, x, agg, N);
    int gblocks = (N + TILE_M - 1) / TILE_M;
    sage_gemm_kernel<1, 0><<<gblocks, 256, 0, stream>>>(agg, x, w1n, w1r, b1, h1, nullptr, N);

    // ---- layer 2 (pool fused into epilogue) ----
    gather_agg_kernel<<<ablocks, 256, 0, stream>>>(row_start, col_idx, rdeg, h1, agg, N);
    sage_gemm_kernel<0, 1><<<gblocks, 256, 0, stream>>>(agg, h1, w2n, w2r, b2, pooled, batch, N);

    final_kernel<<<G_NUM, D, 0, stream>>>(pooled, cnt, fcw, fcb, out);
}

// Round 5
// 442.047 us; speedup vs baseline: 7.1874x; 1.8588x over previous
//
#include <hip/hip_runtime.h>

#define D 128
#define G_NUM 512

typedef unsigned short u16;
typedef __attribute__((ext_vector_type(8))) short bf16x8;
typedef __attribute__((ext_vector_type(4))) float f32x4;

__device__ __forceinline__ float bf2f(u16 u) {
    return __uint_as_float(((unsigned int)u) << 16);
}
__device__ __forceinline__ u16 f2bf_rne(float f) {
    unsigned int u = __float_as_uint(f);
    unsigned int r = (u + 0x7FFFu + ((u >> 16) & 1u)) >> 16;
    return (u16)r;
}
__device__ __forceinline__ void split_bf16(float v, u16& h, u16& l) {
    h = f2bf_rne(v);
    l = f2bf_rne(v - bf2f(h));
}

// ---------------- in-degree histogram ----------------
__global__ void deg_kernel(const int* __restrict__ tgt, int* __restrict__ deg, int E) {
    int e = blockIdx.x * blockDim.x + threadIdx.x;
    if (e < E) atomicAdd(&deg[tgt[e]], 1);
}

// ---------------- block-level exclusive scan (step 1) ----------------
__global__ void scan1_kernel(const int* __restrict__ deg, int* __restrict__ row_excl,
                             int* __restrict__ partial, int N) {
    __shared__ int s[256];
    int t = threadIdx.x, i = blockIdx.x * 256 + t;
    int v = (i < N) ? deg[i] : 0;
    s[t] = v;
    __syncthreads();
    for (int off = 1; off < 256; off <<= 1) {
        int add = (t >= off) ? s[t - off] : 0;
        __syncthreads();
        s[t] += add;
        __syncthreads();
    }
    if (i < N) row_excl[i] = s[t] - v;
    if (t == 255) partial[blockIdx.x] = s[255];
}

__global__ void scan2_kernel(int* __restrict__ partial, int NB) {
    __shared__ int s[256];
    int t = threadIdx.x;
    int v = (t < NB) ? partial[t] : 0;
    s[t] = v;
    __syncthreads();
    for (int off = 1; off < 256; off <<= 1) {
        int add = (t >= off) ? s[t - off] : 0;
        __syncthreads();
        s[t] += add;
        __syncthreads();
    }
    if (t < NB) partial[t] = s[t] - v;
}

__global__ void scan3_kernel(int* __restrict__ row_start, const int* __restrict__ partial,
                             int* __restrict__ deg, float* __restrict__ rdeg, int N, int E) {
    int i = blockIdx.x * blockDim.x + threadIdx.x;
    if (i < N) {
        row_start[i] += partial[blockIdx.x];
        float d = (float)deg[i];
        rdeg[i] = 1.0f / fmaxf(d, 1.0f);
        deg[i] = 0;  // becomes fill cursor
    }
    if (i == 0) row_start[N] = E;
}

__global__ void fill_kernel(const int* __restrict__ src, const int* __restrict__ tgt,
                            const int* __restrict__ row_start, int* __restrict__ cursor,
                            int* __restrict__ col_idx, int E) {
    int e = blockIdx.x * blockDim.x + threadIdx.x;
    if (e >= E) return;
    int t = tgt[e];
    int pos = row_start[t] + atomicAdd(&cursor[t], 1);
    col_idx[pos] = src[e];
}

// ---------------- graph boundaries from sorted batch ----------------
__global__ void boundary_kernel(const int* __restrict__ batch, int* __restrict__ gstart, int N) {
    int i = blockIdx.x * blockDim.x + threadIdx.x;
    if (i >= N) return;
    int b = batch[i];
    int bp = (i == 0) ? -1 : batch[i - 1];
    for (int g = bp + 1; g <= b; g++) gstart[g] = i;
    if (i == N - 1)
        for (int g = b + 1; g <= G_NUM; g++) gstart[g] = N;
}

// ---------------- x -> bf16 hi/lo ----------------
__global__ void convert_x_kernel(const float* __restrict__ x, u16* __restrict__ xh,
                                 u16* __restrict__ xl, int n4) {
    int i = blockIdx.x * blockDim.x + threadIdx.x;
    if (i >= n4) return;
    float4 v = ((const float4*)x)[i];
    ushort4 h, l;
    split_bf16(v.x, h.x, l.x);
    split_bf16(v.y, h.y, l.y);
    split_bf16(v.z, h.z, l.z);
    split_bf16(v.w, h.w, l.w);
    ((ushort4*)xh)[i] = h;
    ((ushort4*)xl)[i] = l;
}

// ---------------- pack 4 weight matrices into MFMA B-fragment order, hi/lo ----------------
// out idx = mat*32768 + {0|16384} + ((kt*128 + c)*4 + g)*8 + j, value W[(kt*32+g*8+j)][c]
__global__ void convert_w_kernel(const float* __restrict__ w0, const float* __restrict__ w1,
                                 const float* __restrict__ w2, const float* __restrict__ w3,
                                 u16* __restrict__ wp) {
    int t = blockIdx.x * blockDim.x + threadIdx.x;
    if (t >= 8192) return;
    int g = t & 3, c = (t >> 2) & 127, kt = (t >> 9) & 3, mat = t >> 11;
    const float* W = (mat == 0) ? w0 : (mat == 1) ? w1 : (mat == 2) ? w2 : w3;
    u16* dh = wp + mat * 32768 + ((size_t)(kt * 128 + c) * 4 + g) * 8;
    u16* dl = dh + 16384;
#pragma unroll
    for (int j = 0; j < 8; j++) {
        float v = W[(size_t)(kt * 32 + g * 8 + j) * D + c];
        u16 h, l;
        split_bf16(v, h, l);
        dh[j] = h;
        dl[j] = l;
    }
}

// ---------------- CSR mean-gather -> bf16 hi/lo agg ----------------
// 8 nodes / 256-thread block; 32 lanes per node, float4 per lane, 4-edge unroll.
template <int BF16IN>
__global__ __launch_bounds__(256) void gather_kernel(
    const int* __restrict__ row_start, const int* __restrict__ col_idx,
    const float* __restrict__ rdeg, const float* __restrict__ feat32,
    const u16* __restrict__ fhi, const u16* __restrict__ flo,
    u16* __restrict__ agg_hi, u16* __restrict__ agg_lo, int N) {
    int node = blockIdx.x * 8 + (threadIdx.x >> 5);
    if (node >= N) return;
    int q = threadIdx.x & 31;
    int beg = row_start[node], end = row_start[node + 1];
    float ax = 0.f, ay = 0.f, az = 0.f, aw = 0.f;
    int i = beg;
    for (; i + 4 <= end; i += 4) {
        int s0 = col_idx[i], s1 = col_idx[i + 1], s2 = col_idx[i + 2], s3 = col_idx[i + 3];
        if (BF16IN) {
            ushort4 h0 = *(const ushort4*)(fhi + (size_t)s0 * D + q * 4);
            ushort4 l0 = *(const ushort4*)(flo + (size_t)s0 * D + q * 4);
            ushort4 h1 = *(const ushort4*)(fhi + (size_t)s1 * D + q * 4);
            ushort4 l1 = *(const ushort4*)(flo + (size_t)s1 * D + q * 4);
            ushort4 h2 = *(const ushort4*)(fhi + (size_t)s2 * D + q * 4);
            ushort4 l2 = *(const ushort4*)(flo + (size_t)s2 * D + q * 4);
            ushort4 h3 = *(const ushort4*)(fhi + (size_t)s3 * D + q * 4);
            ushort4 l3 = *(const ushort4*)(flo + (size_t)s3 * D + q * 4);
            ax += bf2f(h0.x) + bf2f(l0.x) + bf2f(h1.x) + bf2f(l1.x) +
                  bf2f(h2.x) + bf2f(l2.x) + bf2f(h3.x) + bf2f(l3.x);
            ay += bf2f(h0.y) + bf2f(l0.y) + bf2f(h1.y) + bf2f(l1.y) +
                  bf2f(h2.y) + bf2f(l2.y) + bf2f(h3.y) + bf2f(l3.y);
            az += bf2f(h0.z) + bf2f(l0.z) + bf2f(h1.z) + bf2f(l1.z) +
                  bf2f(h2.z) + bf2f(l2.z) + bf2f(h3.z) + bf2f(l3.z);
            aw += bf2f(h0.w) + bf2f(l0.w) + bf2f(h1.w) + bf2f(l1.w) +
                  bf2f(h2.w) + bf2f(l2.w) + bf2f(h3.w) + bf2f(l3.w);
        } else {
            float4 v0 = ((const float4*)feat32)[(size_t)s0 * 32 + q];
            float4 v1 = ((const float4*)feat32)[(size_t)s1 * 32 + q];
            float4 v2 = ((const float4*)feat32)[(size_t)s2 * 32 + q];
            float4 v3 = ((const float4*)feat32)[(size_t)s3 * 32 + q];
            ax += v0.x + v1.x + v2.x + v3.x;
            ay += v0.y + v1.y + v2.y + v3.y;
            az += v0.z + v1.z + v2.z + v3.z;
            aw += v0.w + v1.w + v2.w + v3.w;
        }
    }
    for (; i < end; i++) {
        int s = col_idx[i];
        if (BF16IN) {
            ushort4 h = *(const ushort4*)(fhi + (size_t)s * D + q * 4);
            ushort4 l = *(const ushort4*)(flo + (size_t)s * D + q * 4);
            ax += bf2f(h.x) + bf2f(l.x);
            ay += bf2f(h.y) + bf2f(l.y);
            az += bf2f(h.z) + bf2f(l.z);
            aw += bf2f(h.w) + bf2f(l.w);
        } else {
            float4 v = ((const float4*)feat32)[(size_t)s * 32 + q];
            ax += v.x;
            ay += v.y;
            az += v.z;
            aw += v.w;
        }
    }
    float rd = rdeg[node];
    ax *= rd; ay *= rd; az *= rd; aw *= rd;
    ushort4 hv, lv;
    split_bf16(ax, hv.x, lv.x);
    split_bf16(ay, hv.y, lv.y);
    split_bf16(az, hv.z, lv.z);
    split_bf16(aw, hv.w, lv.w);
    *(ushort4*)(agg_hi + (size_t)node * D + q * 4) = hv;
    *(ushort4*)(agg_lo + (size_t)node * D + q * 4) = lv;
}

// ---------------- MFMA GEMM: out = Agg@Wn + X@Wr + b  (split-bf16, 3 terms each) ----------------
// Grid: ceil(N/64) blocks x 256 threads (4 waves). Wave w: rows [blk*64+w*16, +16), all 128 cols.
// No LDS. A frags from row-major bf16 global; B frags from pre-packed weight arrays.
// MODE 0: relu, write out_hi/out_lo bf16.  MODE 1: write out_f32.
template <int MODE>
__global__ __launch_bounds__(256) void mfma_gemm_kernel(
    const u16* __restrict__ Ah, const u16* __restrict__ Al,
    const u16* __restrict__ Xh, const u16* __restrict__ Xl,
    const u16* __restrict__ Wnh, const u16* __restrict__ Wnl,
    const u16* __restrict__ Wrh, const u16* __restrict__ Wrl,
    const float* __restrict__ bias, float* __restrict__ out_f32,
    u16* __restrict__ out_hi, u16* __restrict__ out_lo, int N) {
    int wave = threadIdx.x >> 6;
    int lane = threadIdx.x & 63;
    int row0 = blockIdx.x * 64 + wave * 16;
    int r = lane & 15, g = lane >> 4;

    int arow = min(row0 + r, N - 1);
    size_t abase = (size_t)arow * D + g * 8;

    f32x4 acc[8];
#pragma unroll
    for (int ct = 0; ct < 8; ct++) acc[ct] = (f32x4){0.f, 0.f, 0.f, 0.f};

#pragma unroll
    for (int kt = 0; kt < 4; kt++) {
        bf16x8 ah = *(const bf16x8*)(Ah + abase + kt * 32);
        bf16x8 al = *(const bf16x8*)(Al + abase + kt * 32);
        bf16x8 xh = *(const bf16x8*)(Xh + abase + kt * 32);
        bf16x8 xl = *(const bf16x8*)(Xl + abase + kt * 32);
        size_t wb = ((size_t)(kt * 128 + r) * 4 + g) * 8;
#pragma unroll
        for (int ct = 0; ct < 8; ct++) {
            size_t wo = wb + (size_t)ct * 512;  // ct*16 cols * 32 shorts/col
            bf16x8 bnh = *(const bf16x8*)(Wnh + wo);
            bf16x8 bnl = *(const bf16x8*)(Wnl + wo);
            bf16x8 brh = *(const bf16x8*)(Wrh + wo);
            bf16x8 brl = *(const bf16x8*)(Wrl + wo);
            acc[ct] = __builtin_amdgcn_mfma_f32_16x16x32_bf16(ah, bnh, acc[ct], 0, 0, 0);
            acc[ct] = __builtin_amdgcn_mfma_f32_16x16x32_bf16(al, bnh, acc[ct], 0, 0, 0);
            acc[ct] = __builtin_amdgcn_mfma_f32_16x16x32_bf16(ah, bnl, acc[ct], 0, 0, 0);
            acc[ct] = __builtin_amdgcn_mfma_f32_16x16x32_bf16(xh, brh, acc[ct], 0, 0, 0);
            acc[ct] = __builtin_amdgcn_mfma_f32_16x16x32_bf16(xl, brh, acc[ct], 0, 0, 0);
            acc[ct] = __builtin_amdgcn_mfma_f32_16x16x32_bf16(xh, brl, acc[ct], 0, 0, 0);
        }
    }

#pragma unroll
    for (int ct = 0; ct < 8; ct++) {
        int col = ct * 16 + r;
        float bv = bias[col];
#pragma unroll
        for (int reg = 0; reg < 4; reg++) {
            int row = row0 + g * 4 + reg;  // C/D: col=lane&15, row=(lane>>4)*4+reg
            if (row >= N) continue;
            float v = acc[ct][reg] + bv;
            if (MODE == 0) {
                v = fmaxf(v, 0.f);
                u16 h, l;
                split_bf16(v, h, l);
                out_hi[(size_t)row * D + col] = h;
                out_lo[(size_t)row * D + col] = l;
            } else {
                out_f32[(size_t)row * D + col] = v;
            }
        }
    }
}

// ---------------- per-graph mean pool + FC ----------------
__global__ __launch_bounds__(128) void pool_fc_kernel(
    const float* __restrict__ h2, const int* __restrict__ gstart,
    const float* __restrict__ fcw, const float* __restrict__ fcb, float* __restrict__ out) {
    __shared__ float p[D];
    int g = blockIdx.x, t = threadIdx.x;
    int s = gstart[g], e = gstart[g + 1];
    float acc = 0.f;
    for (int r = s; r < e; r++) acc += h2[(size_t)r * D + t];
    float rc = 1.0f / fmaxf((float)(e - s), 1.0f);
    p[t] = acc * rc;
    __syncthreads();
    if (t < 10) {
        float o = fcb[t];
#pragma unroll
        for (int k = 0; k < D; k++) o += p[k] * fcw[k * 10 + t];
        out[g * 10 + t] = o;
    }
}

extern "C" void kernel_launch(void* const* d_in, const int* in_sizes, int n_in,
                              void* d_out, int out_size, void* d_ws, size_t ws_size,
                              hipStream_t stream) {
    const float* x   = (const float*)d_in[0];
    const int*   ei  = (const int*)d_in[1];
    const int* batch = (const int*)d_in[2];
    const float* w1n = (const float*)d_in[3];
    const float* b1  = (const float*)d_in[4];
    const float* w1r = (const float*)d_in[5];
    const float* w2n = (const float*)d_in[6];
    const float* b2  = (const float*)d_in[7];
    const float* w2r = (const float*)d_in[8];
    const float* fcw = (const float*)d_in[9];
    const float* fcb = (const float*)d_in[10];
    float* out = (float*)d_out;

    int N = in_sizes[0] / D;
    int E = in_sizes[1] / 2;
    const int* src = ei;
    const int* tgt = ei + E;
    int NB = (N + 255) / 256;

    // ---- workspace layout (256B-aligned regions) ----
    auto au = [](size_t v) { return (v + 255) & ~(size_t)255; };
    char* p = (char*)d_ws;
    int*   deg       = (int*)p;    p += au((size_t)N * 4);
    int*   row_start = (int*)p;    p += au((size_t)(N + 1) * 4);
    int*   partial   = (int*)p;    p += au(256 * 4);
    int*   col_idx   = (int*)p;    p += au((size_t)E * 4);
    float* rdeg      = (float*)p;  p += au((size_t)N * 4);
    int*   gstart    = (int*)p;    p += au((size_t)(G_NUM + 1) * 4);
    u16*   wp        = (u16*)p;    p += au((size_t)8 * 16384 * 2);
    u16*   xh        = (u16*)p;    p += au((size_t)N * D * 2);
    u16*   xl        = (u16*)p;    p += au((size_t)N * D * 2);
    u16*   aggh      = (u16*)p;    p += au((size_t)N * D * 2);
    u16*   aggl      = (u16*)p;    p += au((size_t)N * D * 2);
    u16*   h1h       = (u16*)p;    p += au((size_t)N * D * 2);
    u16*   h1l       = (u16*)p;    p += au((size_t)N * D * 2);
    float* h2        = (float*)xh;  // alias: xh+xl region (dead after GEMM1), exactly N*D*4 bytes

    hipMemsetAsync(deg, 0, (size_t)N * 4, stream);

    // ---- CSR build (reused by both layers) ----
    deg_kernel<<<(E + 255) / 256, 256, 0, stream>>>(tgt, deg, E);
    scan1_kernel<<<NB, 256, 0, stream>>>(deg, row_start, partial, N);
    scan2_kernel<<<1, 256, 0, stream>>>(partial, NB);
    scan3_kernel<<<NB, 256, 0, stream>>>(row_start, partial, deg, rdeg, N, E);
    fill_kernel<<<(E + 255) / 256, 256, 0, stream>>>(src, tgt, row_start, deg, col_idx, E);

    // ---- one-time conversions + graph boundaries ----
    convert_x_kernel<<<(N * 32 + 255) / 256, 256, 0, stream>>>(x, xh, xl, N * 32);
    convert_w_kernel<<<32, 256, 0, stream>>>(w1n, w1r, w2n, w2r, wp);
    boundary_kernel<<<NB, 256, 0, stream>>>(batch, gstart, N);

    int gb = (N + 7) / 8;
    int mb = (N + 63) / 64;

    // ---- layer 1 ----
    gather_kernel<0><<<gb, 256, 0, stream>>>(row_start, col_idx, rdeg, x, nullptr, nullptr,
                                             aggh, aggl, N);
    mfma_gemm_kernel<0><<<mb, 256, 0, stream>>>(aggh, aggl, xh, xl,
                                                wp + 0 * 32768, wp + 0 * 32768 + 16384,
                                                wp + 1 * 32768, wp + 1 * 32768 + 16384,
                                                b1, nullptr, h1h, h1l, N);

    // ---- layer 2 ----
    gather_kernel<1><<<gb, 256, 0, stream>>>(row_start, col_idx, rdeg, nullptr, h1h, h1l,
                                             aggh, aggl, N);
    mfma_gemm_kernel<1><<<mb, 256, 0, stream>>>(aggh, aggl, h1h, h1l,
                                                wp + 2 * 32768, wp + 2 * 32768 + 16384,
                                                wp + 3 * 32768, wp + 3 * 32768 + 16384,
                                                b2, h2, nullptr, nullptr, N);

    // ---- pool + FC ----
    pool_fc_kernel<<<G_NUM, 128, 0, stream>>>(h2, gstart, fcw, fcb, out);
}

// Round 6
// 390.197 us; speedup vs baseline: 8.1425x; 1.1329x over previous
//
#include <hip/hip_runtime.h>

#define D 128
#define G_NUM 512

typedef unsigned short u16;
typedef unsigned int u32;
typedef __attribute__((ext_vector_type(8))) short bf16x8;
typedef __attribute__((ext_vector_type(4))) float f32x4;

__device__ __forceinline__ float bf2f(u16 u) {
    return __uint_as_float(((u32)u) << 16);
}
__device__ __forceinline__ u16 f2bf_rne(float f) {
    u32 u = __float_as_uint(f);
    u32 r = (u + 0x7FFFu + ((u >> 16) & 1u)) >> 16;
    return (u16)r;
}
__device__ __forceinline__ void split_bf16(float v, u16& h, u16& l) {
    h = f2bf_rne(v);
    l = f2bf_rne(v - bf2f(h));
}
// packed u32 = (hi<<16)|lo ; hi value = as_float(u & 0xFFFF0000), lo value = as_float(u<<16)
__device__ __forceinline__ float pk_hi(u32 u) { return __uint_as_float(u & 0xFFFF0000u); }
__device__ __forceinline__ float pk_lo(u32 u) { return __uint_as_float(u << 16); }
__device__ __forceinline__ bf16x8 mk8(u32 a, u32 b, u32 c, u32 d) {
    union { u32 u[4]; bf16x8 v; } t;
    t.u[0] = a; t.u[1] = b; t.u[2] = c; t.u[3] = d;
    return t.v;
}

// ---------------- fused prep: convert_x | deg histogram | convert_w | boundary ----------------
__global__ void prep_kernel(const float* __restrict__ x, u16* __restrict__ xh, u16* __restrict__ xl,
                            const float* __restrict__ w0, const float* __restrict__ w1,
                            const float* __restrict__ w2, const float* __restrict__ w3,
                            u16* __restrict__ wp,
                            const int* __restrict__ batch, int* __restrict__ gstart,
                            const int* __restrict__ tgt, int* __restrict__ deg,
                            int n4, int E, int N, int NBX, int NBE) {
    int b = blockIdx.x, t = threadIdx.x;
    if (b < NBX) {  // x -> bf16 hi/lo (float4 per thread)
        int i = b * 256 + t;
        if (i >= n4) return;
        float4 v = ((const float4*)x)[i];
        ushort4 h, l;
        split_bf16(v.x, h.x, l.x);
        split_bf16(v.y, h.y, l.y);
        split_bf16(v.z, h.z, l.z);
        split_bf16(v.w, h.w, l.w);
        ((ushort4*)xh)[i] = h;
        ((ushort4*)xl)[i] = l;
    } else if (b < NBX + NBE) {  // in-degree histogram
        int e = (b - NBX) * 256 + t;
        if (e < E) atomicAdd(&deg[tgt[e]], 1);
    } else if (b < NBX + NBE + 32) {  // pack weights into MFMA B-fragment order, hi/lo
        int id = (b - NBX - NBE) * 256 + t;
        int g = id & 3, c = (id >> 2) & 127, kt = (id >> 9) & 3, mat = id >> 11;
        const float* W = (mat == 0) ? w0 : (mat == 1) ? w1 : (mat == 2) ? w2 : w3;
        u16* dh = wp + mat * 32768 + ((size_t)(kt * 128 + c) * 4 + g) * 8;
        u16* dl = dh + 16384;
#pragma unroll
        for (int j = 0; j < 8; j++) {
            float v = W[(size_t)(kt * 32 + g * 8 + j) * D + c];
            u16 h, l;
            split_bf16(v, h, l);
            dh[j] = h;
            dl[j] = l;
        }
    } else {  // graph boundaries from sorted batch
        int i = (b - NBX - NBE - 32) * 256 + t;
        if (i >= N) return;
        int bb = batch[i];
        int bp = (i == 0) ? -1 : batch[i - 1];
        for (int g = bp + 1; g <= bb; g++) gstart[g] = i;
        if (i == N - 1)
            for (int g = bb + 1; g <= G_NUM; g++) gstart[g] = N;
    }
}

// ---------------- block-level exclusive scan ----------------
__global__ void scan1_kernel(const int* __restrict__ deg, int* __restrict__ row_excl,
                             int* __restrict__ partial, int N) {
    __shared__ int s[256];
    int t = threadIdx.x, i = blockIdx.x * 256 + t;
    int v = (i < N) ? deg[i] : 0;
    s[t] = v;
    __syncthreads();
    for (int off = 1; off < 256; off <<= 1) {
        int add = (t >= off) ? s[t - off] : 0;
        __syncthreads();
        s[t] += add;
        __syncthreads();
    }
    if (i < N) row_excl[i] = s[t] - v;
    if (t == 255) partial[blockIdx.x] = s[255];
}

__global__ void scan2_kernel(int* __restrict__ partial, int NB) {
    __shared__ int s[256];
    int t = threadIdx.x;
    int v = (t < NB) ? partial[t] : 0;
    s[t] = v;
    __syncthreads();
    for (int off = 1; off < 256; off <<= 1) {
        int add = (t >= off) ? s[t - off] : 0;
        __syncthreads();
        s[t] += add;
        __syncthreads();
    }
    if (t < NB) partial[t] = s[t] - v;
}

__global__ void scan3_kernel(int* __restrict__ row_start, const int* __restrict__ partial,
                             int* __restrict__ deg, float* __restrict__ rdeg, int N, int E) {
    int i = blockIdx.x * blockDim.x + threadIdx.x;
    if (i < N) {
        row_start[i] += partial[blockIdx.x];
        float d = (float)deg[i];
        rdeg[i] = 1.0f / fmaxf(d, 1.0f);
        deg[i] = 0;  // becomes fill cursor
    }
    if (i == 0) row_start[N] = E;
}

__global__ void fill_kernel(const int* __restrict__ src, const int* __restrict__ tgt,
                            const int* __restrict__ row_start, int* __restrict__ cursor,
                            int* __restrict__ col_idx, int E) {
    int e = blockIdx.x * blockDim.x + threadIdx.x;
    if (e >= E) return;
    int t = tgt[e];
    int pos = row_start[t] + atomicAdd(&cursor[t], 1);
    col_idx[pos] = src[e];
}

// ---------------- CSR mean-gather -> bf16 hi/lo agg ----------------
// 8 nodes / 256-thread block; 32 lanes per node; PK=0: f32 input, PK=1: packed-u32 input.
template <int PK>
__global__ __launch_bounds__(256) void gather_kernel(
    const int* __restrict__ row_start, const int* __restrict__ col_idx,
    const float* __restrict__ rdeg, const void* __restrict__ feat,
    u16* __restrict__ agg_hi, u16* __restrict__ agg_lo, int N) {
    int node = blockIdx.x * 8 + (threadIdx.x >> 5);
    if (node >= N) return;
    int q = threadIdx.x & 31;
    int beg = row_start[node], end = row_start[node + 1];
    float ax = 0.f, ay = 0.f, az = 0.f, aw = 0.f;
    int i = beg;
    for (; i + 4 <= end; i += 4) {
        int s0 = col_idx[i], s1 = col_idx[i + 1], s2 = col_idx[i + 2], s3 = col_idx[i + 3];
        if (PK) {
            uint4 v0 = ((const uint4*)feat)[(size_t)s0 * 32 + q];
            uint4 v1 = ((const uint4*)feat)[(size_t)s1 * 32 + q];
            uint4 v2 = ((const uint4*)feat)[(size_t)s2 * 32 + q];
            uint4 v3 = ((const uint4*)feat)[(size_t)s3 * 32 + q];
            ax += (pk_hi(v0.x) + pk_lo(v0.x)) + (pk_hi(v1.x) + pk_lo(v1.x)) +
                  (pk_hi(v2.x) + pk_lo(v2.x)) + (pk_hi(v3.x) + pk_lo(v3.x));
            ay += (pk_hi(v0.y) + pk_lo(v0.y)) + (pk_hi(v1.y) + pk_lo(v1.y)) +
                  (pk_hi(v2.y) + pk_lo(v2.y)) + (pk_hi(v3.y) + pk_lo(v3.y));
            az += (pk_hi(v0.z) + pk_lo(v0.z)) + (pk_hi(v1.z) + pk_lo(v1.z)) +
                  (pk_hi(v2.z) + pk_lo(v2.z)) + (pk_hi(v3.z) + pk_lo(v3.z));
            aw += (pk_hi(v0.w) + pk_lo(v0.w)) + (pk_hi(v1.w) + pk_lo(v1.w)) +
                  (pk_hi(v2.w) + pk_lo(v2.w)) + (pk_hi(v3.w) + pk_lo(v3.w));
        } else {
            float4 v0 = ((const float4*)feat)[(size_t)s0 * 32 + q];
            float4 v1 = ((const float4*)feat)[(size_t)s1 * 32 + q];
            float4 v2 = ((const float4*)feat)[(size_t)s2 * 32 + q];
            float4 v3 = ((const float4*)feat)[(size_t)s3 * 32 + q];
            ax += v0.x + v1.x + v2.x + v3.x;
            ay += v0.y + v1.y + v2.y + v3.y;
            az += v0.z + v1.z + v2.z + v3.z;
            aw += v0.w + v1.w + v2.w + v3.w;
        }
    }
    for (; i < end; i++) {
        int s = col_idx[i];
        if (PK) {
            uint4 v = ((const uint4*)feat)[(size_t)s * 32 + q];
            ax += pk_hi(v.x) + pk_lo(v.x);
            ay += pk_hi(v.y) + pk_lo(v.y);
            az += pk_hi(v.z) + pk_lo(v.z);
            aw += pk_hi(v.w) + pk_lo(v.w);
        } else {
            float4 v = ((const float4*)feat)[(size_t)s * 32 + q];
            ax += v.x;
            ay += v.y;
            az += v.z;
            aw += v.w;
        }
    }
    float rd = rdeg[node];
    ax *= rd; ay *= rd; az *= rd; aw *= rd;
    ushort4 hv, lv;
    split_bf16(ax, hv.x, lv.x);
    split_bf16(ay, hv.y, lv.y);
    split_bf16(az, hv.z, lv.z);
    split_bf16(aw, hv.w, lv.w);
    *(ushort4*)(agg_hi + (size_t)node * D + q * 4) = hv;
    *(ushort4*)(agg_lo + (size_t)node * D + q * 4) = lv;
}

// ---------------- MFMA GEMM: out = Agg@Wn + X@Wr + b  (split-bf16, 3 terms per operand) ----------------
// Column-split: 4 waves/block, wave w owns cols [w*32, w*32+32) with B fragments preloaded
// into registers ONCE; block grid-strides over 16-row tiles.
// XP=0: X from split xh/xl arrays.  XP=1: X from packed u32 array.
// OUTM=0: relu, write packed u32 (hi<<16|lo).  OUTM=1: write f32.
template <int XP, int OUTM>
__global__ __launch_bounds__(256, 2) void mfma_gemm_kernel(
    const u16* __restrict__ Ah, const u16* __restrict__ Al,
    const u16* __restrict__ Xh, const u16* __restrict__ Xl, const u32* __restrict__ Xp,
    const u16* __restrict__ Wnh, const u16* __restrict__ Wnl,
    const u16* __restrict__ Wrh, const u16* __restrict__ Wrl,
    const float* __restrict__ bias,
    u32* __restrict__ out_pk, float* __restrict__ out_f32, int N, int NT) {
    int wave = threadIdx.x >> 6;
    int lane = threadIdx.x & 63;
    int r = lane & 15, g = lane >> 4;
    int ctBase = wave * 2;

    // ---- preload B fragments into registers (static indexing only) ----
    bf16x8 Bn[2][4][2], Br[2][4][2];  // [ctLocal][kt][hi/lo]
#pragma unroll
    for (int c2 = 0; c2 < 2; c2++)
#pragma unroll
        for (int kt = 0; kt < 4; kt++) {
            size_t wo = ((size_t)(kt * 128 + r) * 4 + g) * 8 + (size_t)(ctBase + c2) * 512;
            Bn[c2][kt][0] = *(const bf16x8*)(Wnh + wo);
            Bn[c2][kt][1] = *(const bf16x8*)(Wnl + wo);
            Br[c2][kt][0] = *(const bf16x8*)(Wrh + wo);
            Br[c2][kt][1] = *(const bf16x8*)(Wrl + wo);
        }
    int col0 = ctBase * 16 + r, col1 = col0 + 16;
    float bv0 = bias[col0], bv1 = bias[col1];

    for (int rt = blockIdx.x; rt < NT; rt += gridDim.x) {
        int row0 = rt * 16;
        int arow = min(row0 + r, N - 1);
        size_t abase = (size_t)arow * D + g * 8;
        f32x4 acc0 = (f32x4){0.f, 0.f, 0.f, 0.f};
        f32x4 acc1 = (f32x4){0.f, 0.f, 0.f, 0.f};
#pragma unroll
        for (int kt = 0; kt < 4; kt++) {
            bf16x8 ah = *(const bf16x8*)(Ah + abase + kt * 32);
            bf16x8 al = *(const bf16x8*)(Al + abase + kt * 32);
            bf16x8 xh, xl;
            if (XP == 0) {
                xh = *(const bf16x8*)(Xh + abase + kt * 32);
                xl = *(const bf16x8*)(Xl + abase + kt * 32);
            } else {
                const u32* xp = Xp + abase + kt * 32;
                uint4 wa = *(const uint4*)(xp);
                uint4 wb = *(const uint4*)(xp + 4);
                xh = mk8((wa.y & 0xFFFF0000u) | (wa.x >> 16),
                         (wa.w & 0xFFFF0000u) | (wa.z >> 16),
                         (wb.y & 0xFFFF0000u) | (wb.x >> 16),
                         (wb.w & 0xFFFF0000u) | (wb.z >> 16));
                xl = mk8((wa.y << 16) | (wa.x & 0xFFFFu),
                         (wa.w << 16) | (wa.z & 0xFFFFu),
                         (wb.y << 16) | (wb.x & 0xFFFFu),
                         (wb.w << 16) | (wb.z & 0xFFFFu));
            }
            acc0 = __builtin_amdgcn_mfma_f32_16x16x32_bf16(ah, Bn[0][kt][0], acc0, 0, 0, 0);
            acc1 = __builtin_amdgcn_mfma_f32_16x16x32_bf16(ah, Bn[1][kt][0], acc1, 0, 0, 0);
            acc0 = __builtin_amdgcn_mfma_f32_16x16x32_bf16(al, Bn[0][kt][0], acc0, 0, 0, 0);
            acc1 = __builtin_amdgcn_mfma_f32_16x16x32_bf16(al, Bn[1][kt][0], acc1, 0, 0, 0);
            acc0 = __builtin_amdgcn_mfma_f32_16x16x32_bf16(ah, Bn[0][kt][1], acc0, 0, 0, 0);
            acc1 = __builtin_amdgcn_mfma_f32_16x16x32_bf16(ah, Bn[1][kt][1], acc1, 0, 0, 0);
            acc0 = __builtin_amdgcn_mfma_f32_16x16x32_bf16(xh, Br[0][kt][0], acc0, 0, 0, 0);
            acc1 = __builtin_amdgcn_mfma_f32_16x16x32_bf16(xh, Br[1][kt][0], acc1, 0, 0, 0);
            acc0 = __builtin_amdgcn_mfma_f32_16x16x32_bf16(xl, Br[0][kt][0], acc0, 0, 0, 0);
            acc1 = __builtin_amdgcn_mfma_f32_16x16x32_bf16(xl, Br[1][kt][0], acc1, 0, 0, 0);
            acc0 = __builtin_amdgcn_mfma_f32_16x16x32_bf16(xh, Br[0][kt][1], acc0, 0, 0, 0);
            acc1 = __builtin_amdgcn_mfma_f32_16x16x32_bf16(xh, Br[1][kt][1], acc1, 0, 0, 0);
        }
#pragma unroll
        for (int reg = 0; reg < 4; reg++) {
            int row = row0 + g * 4 + reg;  // C/D: col=lane&15, row=(lane>>4)*4+reg
            if (row >= N) continue;
            float v0 = acc0[reg] + bv0;
            float v1 = acc1[reg] + bv1;
            if (OUTM == 0) {
                v0 = fmaxf(v0, 0.f);
                v1 = fmaxf(v1, 0.f);
                u16 h, l;
                split_bf16(v0, h, l);
                out_pk[(size_t)row * D + col0] = ((u32)h << 16) | l;
                split_bf16(v1, h, l);
                out_pk[(size_t)row * D + col1] = ((u32)h << 16) | l;
            } else {
                out_f32[(size_t)row * D + col0] = v0;
                out_f32[(size_t)row * D + col1] = v1;
            }
        }
    }
}

// ---------------- per-graph mean pool + FC ----------------
__global__ __launch_bounds__(128) void pool_fc_kernel(
    const float* __restrict__ h2, const int* __restrict__ gstart,
    const float* __restrict__ fcw, const float* __restrict__ fcb, float* __restrict__ out) {
    __shared__ float p[D];
    int g = blockIdx.x, t = threadIdx.x;
    int s = gstart[g], e = gstart[g + 1];
    float acc = 0.f;
    for (int r = s; r < e; r++) acc += h2[(size_t)r * D + t];
    float rc = 1.0f / fmaxf((float)(e - s), 1.0f);
    p[t] = acc * rc;
    __syncthreads();
    if (t < 10) {
        float o = fcb[t];
#pragma unroll
        for (int k = 0; k < D; k++) o += p[k] * fcw[k * 10 + t];
        out[g * 10 + t] = o;
    }
}

extern "C" void kernel_launch(void* const* d_in, const int* in_sizes, int n_in,
                              void* d_out, int out_size, void* d_ws, size_t ws_size,
                              hipStream_t stream) {
    const float* x   = (const float*)d_in[0];
    const int*   ei  = (const int*)d_in[1];
    const int* batch = (const int*)d_in[2];
    const float* w1n = (const float*)d_in[3];
    const float* b1  = (const float*)d_in[4];
    const float* w1r = (const float*)d_in[5];
    const float* w2n = (const float*)d_in[6];
    const float* b2  = (const float*)d_in[7];
    const float* w2r = (const float*)d_in[8];
    const float* fcw = (const float*)d_in[9];
    const float* fcb = (const float*)d_in[10];
    float* out = (float*)d_out;

    int N = in_sizes[0] / D;
    int E = in_sizes[1] / 2;
    const int* src = ei;
    const int* tgt = ei + E;
    int NB = (N + 255) / 256;

    // ---- workspace layout (256B-aligned regions) ----
    auto au = [](size_t v) { return (v + 255) & ~(size_t)255; };
    char* p = (char*)d_ws;
    int*   deg       = (int*)p;    p += au((size_t)N * 4);
    int*   row_start = (int*)p;    p += au((size_t)(N + 1) * 4);
    int*   partial   = (int*)p;    p += au(256 * 4);
    int*   col_idx   = (int*)p;    p += au((size_t)E * 4);
    float* rdeg      = (float*)p;  p += au((size_t)N * 4);
    int*   gstart    = (int*)p;    p += au((size_t)(G_NUM + 1) * 4);
    u16*   wp        = (u16*)p;    p += au((size_t)8 * 16384 * 2);
    u16*   xh        = (u16*)p;    p += au((size_t)N * D * 2);
    u16*   xl        = (u16*)p;    p += au((size_t)N * D * 2);
    u16*   aggh      = (u16*)p;    p += au((size_t)N * D * 2);
    u16*   aggl      = (u16*)p;    p += au((size_t)N * D * 2);
    u32*   h1p       = (u32*)p;    p += au((size_t)N * D * 4);  // packed (hi<<16|lo)
    float* h2        = (float*)xh;  // alias xh+xl (dead after GEMM1), exactly N*D*4 bytes

    hipMemsetAsync(deg, 0, (size_t)N * 4, stream);

    // ---- fused prep: convert_x | deg | convert_w | boundary ----
    int n4 = N * 32;
    int NBX = (n4 + 255) / 256;
    int NBE = (E + 255) / 256;
    prep_kernel<<<NBX + NBE + 32 + NB, 256, 0, stream>>>(
        x, xh, xl, w1n, w1r, w2n, w2r, wp, batch, gstart, tgt, deg, n4, E, N, NBX, NBE);

    // ---- CSR build (reused by both layers) ----
    scan1_kernel<<<NB, 256, 0, stream>>>(deg, row_start, partial, N);
    scan2_kernel<<<1, 256, 0, stream>>>(partial, NB);
    scan3_kernel<<<NB, 256, 0, stream>>>(row_start, partial, deg, rdeg, N, E);
    fill_kernel<<<NBE, 256, 0, stream>>>(src, tgt, row_start, deg, col_idx, E);

    int gb = (N + 7) / 8;
    int NT = (N + 15) / 16;
    int gemm_grid = NT < 500 ? NT : 500;

    // ---- layer 1 ----
    gather_kernel<0><<<gb, 256, 0, stream>>>(row_start, col_idx, rdeg, x, aggh, aggl, N);
    mfma_gemm_kernel<0, 0><<<gemm_grid, 256, 0, stream>>>(
        aggh, aggl, xh, xl, nullptr,
        wp + 0 * 32768, wp + 0 * 32768 + 16384,
        wp + 1 * 32768, wp + 1 * 32768 + 16384,
        b1, h1p, nullptr, N, NT);

    // ---- layer 2 ----
    gather_kernel<1><<<gb, 256, 0, stream>>>(row_start, col_idx, rdeg, h1p, aggh, aggl, N);
    mfma_gemm_kernel<1, 1><<<gemm_grid, 256, 0, stream>>>(
        aggh, aggl, nullptr, nullptr, h1p,
        wp + 2 * 32768, wp + 2 * 32768 + 16384,
        wp + 3 * 32768, wp + 3 * 32768 + 16384,
        b2, nullptr, h2, N, NT);

    // ---- pool + FC ----
    pool_fc_kernel<<<G_NUM, 128, 0, stream>>>(h2, gstart, fcw, fcb, out);
}

// Round 10
// 370.588 us; speedup vs baseline: 8.5733x; 1.0529x over previous
//
#include <hip/hip_runtime.h>

#define D 128
#define G_NUM 512

typedef unsigned short u16;
typedef unsigned int u32;
typedef __attribute__((ext_vector_type(8))) short bf16x8;
typedef __attribute__((ext_vector_type(4))) float f32x4;

__device__ __forceinline__ float bf2f(u16 u) { return __uint_as_float(((u32)u) << 16); }
__device__ __forceinline__ u16 f2bf_rne(float f) {
    u32 u = __float_as_uint(f);
    return (u16)((u + 0x7FFFu + ((u >> 16) & 1u)) >> 16);
}
// packed u32 = (hi<<16)|lo, value ~= f to ~2^-17 rel
__device__ __forceinline__ u32 packf(float v) {
    u16 h = f2bf_rne(v);
    u16 l = f2bf_rne(v - bf2f(h));
    return ((u32)h << 16) | l;
}
__device__ __forceinline__ float pk_hi(u32 u) { return __uint_as_float(u & 0xFFFF0000u); }
__device__ __forceinline__ float pk_lo(u32 u) { return __uint_as_float(u << 16); }

// 8 packed u32 -> hi/lo bf16x8 fragments
__device__ __forceinline__ void unpack8(const u32* w, bf16x8& hi, bf16x8& lo) {
    union { u32 u[4]; bf16x8 v; } H, L;
#pragma unroll
    for (int p = 0; p < 4; p++) {
        u32 a = w[2 * p], b = w[2 * p + 1];
        H.u[p] = (b & 0xFFFF0000u) | (a >> 16);
        L.u[p] = (b << 16) | (a & 0xFFFFu);
    }
    hi = H.v;
    lo = L.v;
}

// ---------------- fused prep: x->packed | deg histogram | weight pack | boundary ----------------
__global__ void prep_kernel(const float* __restrict__ x, u32* __restrict__ xp,
                            const float* __restrict__ w0, const float* __restrict__ w1,
                            const float* __restrict__ w2, const float* __restrict__ w3,
                            u16* __restrict__ wp,
                            const int* __restrict__ batch, int* __restrict__ gstart,
                            const int* __restrict__ tgt, int* __restrict__ deg,
                            int n4, int E, int N, int NBX, int NBE) {
    int b = blockIdx.x, t = threadIdx.x;
    if (b < NBX) {  // x -> packed bf16 hi|lo
        int i = b * 256 + t;
        if (i >= n4) return;
        float4 v = ((const float4*)x)[i];
        uint4 o;
        o.x = packf(v.x);
        o.y = packf(v.y);
        o.z = packf(v.z);
        o.w = packf(v.w);
        ((uint4*)xp)[i] = o;
    } else if (b < NBX + NBE) {  // in-degree histogram
        int e = (b - NBX) * 256 + t;
        if (e < E) atomicAdd(&deg[tgt[e]], 1);
    } else if (b < NBX + NBE + 32) {  // pack weights into MFMA B-fragment order, hi/lo
        int id = (b - NBX - NBE) * 256 + t;
        int g = id & 3, c = (id >> 2) & 127, kt = (id >> 9) & 3, mat = id >> 11;
        const float* W = (mat == 0) ? w0 : (mat == 1) ? w1 : (mat == 2) ? w2 : w3;
        u16* dh = wp + mat * 32768 + ((size_t)(kt * 128 + c) * 4 + g) * 8;
        u16* dl = dh + 16384;
#pragma unroll
        for (int j = 0; j < 8; j++) {
            float v = W[(size_t)(kt * 32 + g * 8 + j) * D + c];
            u16 h = f2bf_rne(v);
            dh[j] = h;
            dl[j] = f2bf_rne(v - bf2f(h));
        }
    } else {  // graph boundaries from sorted batch
        int i = (b - NBX - NBE - 32) * 256 + t;
        if (i >= N) return;
        int bb = batch[i];
        int bp = (i == 0) ? -1 : batch[i - 1];
        for (int g = bp + 1; g <= bb; g++) gstart[g] = i;
        if (i == N - 1)
            for (int g = bb + 1; g <= G_NUM; g++) gstart[g] = N;
    }
}

// ---------------- block-level exclusive scan ----------------
__global__ void scan1_kernel(const int* __restrict__ deg, int* __restrict__ row_excl,
                             int* __restrict__ partial, int N) {
    __shared__ int s[256];
    int t = threadIdx.x, i = blockIdx.x * 256 + t;
    int v = (i < N) ? deg[i] : 0;
    s[t] = v;
    __syncthreads();
    for (int off = 1; off < 256; off <<= 1) {
        int add = (t >= off) ? s[t - off] : 0;
        __syncthreads();
        s[t] += add;
        __syncthreads();
    }
    if (i < N) row_excl[i] = s[t] - v;
    if (t == 255) partial[blockIdx.x] = s[255];
}

__global__ void scan2_kernel(int* __restrict__ partial, int NB) {
    __shared__ int s[256];
    int t = threadIdx.x;
    int v = (t < NB) ? partial[t] : 0;
    s[t] = v;
    __syncthreads();
    for (int off = 1; off < 256; off <<= 1) {
        int add = (t >= off) ? s[t - off] : 0;
        __syncthreads();
        s[t] += add;
        __syncthreads();
    }
    if (t < NB) partial[t] = s[t] - v;
}

__global__ void scan3_kernel(int* __restrict__ row_start, const int* __restrict__ partial,
                             int* __restrict__ deg, float* __restrict__ rdeg, int N, int E) {
    int i = blockIdx.x * blockDim.x + threadIdx.x;
    if (i < N) {
        row_start[i] += partial[blockIdx.x];
        float d = (float)deg[i];
        rdeg[i] = 1.0f / fmaxf(d, 1.0f);
        deg[i] = 0;  // becomes fill cursor
    }
    if (i == 0) row_start[N] = E;
}

__global__ void fill_kernel(const int* __restrict__ src, const int* __restrict__ tgt,
                            const int* __restrict__ row_start, int* __restrict__ cursor,
                            int* __restrict__ col_idx, int E) {
    int e = blockIdx.x * blockDim.x + threadIdx.x;
    if (e >= E) return;
    int t = tgt[e];
    int pos = row_start[t] + atomicAdd(&cursor[t], 1);
    col_idx[pos] = src[e];
}

// ---------------- fused SAGE layer: gather(mean) + MFMA GEMM ----------------
// 512 threads = 8 waves, 2 blocks/CU. Per 16-row tile (grid-stride):
//   gather phase: 16 nodes x 32 lanes, CSR mean from packed feat -> LDS (packed, stride 132)
//   mfma phase:   wave w owns cols [w*16,w*16+16), B fragments register-resident,
//                 A from LDS, X row from packed feat global; split-bf16 3-term per operand.
// LAYER 0: relu, write packed u32 h1p.  LAYER 1: write f32 h2.
template <int LAYER>
__global__ __launch_bounds__(512, 4) void sage_fused_kernel(
    const int* __restrict__ row_start, const int* __restrict__ col_idx,
    const float* __restrict__ rdeg, const u32* __restrict__ feat_pk,
    const u16* __restrict__ Wnh, const u16* __restrict__ Wnl,
    const u16* __restrict__ Wrh, const u16* __restrict__ Wrl,
    const float* __restrict__ bias, u32* __restrict__ out_pk,
    float* __restrict__ out_f32, int N, int NT) {
    __shared__ u32 agg[16 * 132];  // packed bf16 hi|lo, stride 132 u32 (bank-spread)

    int tid = threadIdx.x;
    int lane = tid & 63;
    int wave = tid >> 6;  // = ct (16-col slice)
    int r = lane & 15, g = lane >> 4;

    // ---- preload B fragments (1 ct x 4 kt x {Wn,Wr} x {hi,lo} = 16 bf16x8 = 64 VGPR) ----
    bf16x8 Bn[4][2], Br[4][2];
#pragma unroll
    for (int kt = 0; kt < 4; kt++) {
        size_t wo = ((size_t)(kt * 128 + r) * 4 + g) * 8 + (size_t)wave * 512;
        Bn[kt][0] = *(const bf16x8*)(Wnh + wo);
        Bn[kt][1] = *(const bf16x8*)(Wnl + wo);
        Br[kt][0] = *(const bf16x8*)(Wrh + wo);
        Br[kt][1] = *(const bf16x8*)(Wrl + wo);
    }
    float bv = bias[wave * 16 + r];

    int nl = tid >> 5;  // node-local 0..15
    int q = tid & 31;   // feature quad 0..31

    for (int rt = blockIdx.x; rt < NT; rt += gridDim.x) {
        // ---------- gather phase ----------
        int node = rt * 16 + nl;
        float ax = 0.f, ay = 0.f, az = 0.f, aw = 0.f;
        if (node < N) {
            int beg = row_start[node], end = row_start[node + 1];
            int i = beg;
            for (; i + 4 <= end; i += 4) {
                int s0 = col_idx[i], s1 = col_idx[i + 1], s2 = col_idx[i + 2], s3 = col_idx[i + 3];
                uint4 v0 = ((const uint4*)feat_pk)[(size_t)s0 * 32 + q];
                uint4 v1 = ((const uint4*)feat_pk)[(size_t)s1 * 32 + q];
                uint4 v2 = ((const uint4*)feat_pk)[(size_t)s2 * 32 + q];
                uint4 v3 = ((const uint4*)feat_pk)[(size_t)s3 * 32 + q];
                ax += (pk_hi(v0.x) + pk_lo(v0.x)) + (pk_hi(v1.x) + pk_lo(v1.x)) +
                      (pk_hi(v2.x) + pk_lo(v2.x)) + (pk_hi(v3.x) + pk_lo(v3.x));
                ay += (pk_hi(v0.y) + pk_lo(v0.y)) + (pk_hi(v1.y) + pk_lo(v1.y)) +
                      (pk_hi(v2.y) + pk_lo(v2.y)) + (pk_hi(v3.y) + pk_lo(v3.y));
                az += (pk_hi(v0.z) + pk_lo(v0.z)) + (pk_hi(v1.z) + pk_lo(v1.z)) +
                      (pk_hi(v2.z) + pk_lo(v2.z)) + (pk_hi(v3.z) + pk_lo(v3.z));
                aw += (pk_hi(v0.w) + pk_lo(v0.w)) + (pk_hi(v1.w) + pk_lo(v1.w)) +
                      (pk_hi(v2.w) + pk_lo(v2.w)) + (pk_hi(v3.w) + pk_lo(v3.w));
            }
            for (; i < end; i++) {
                int s = col_idx[i];
                uint4 v = ((const uint4*)feat_pk)[(size_t)s * 32 + q];
                ax += pk_hi(v.x) + pk_lo(v.x);
                ay += pk_hi(v.y) + pk_lo(v.y);
                az += pk_hi(v.z) + pk_lo(v.z);
                aw += pk_hi(v.w) + pk_lo(v.w);
            }
            float rd = rdeg[node];
            ax *= rd; ay *= rd; az *= rd; aw *= rd;
        }
        uint4 pk4;
        pk4.x = packf(ax);
        pk4.y = packf(ay);
        pk4.z = packf(az);
        pk4.w = packf(aw);
        *(uint4*)&agg[nl * 132 + q * 4] = pk4;
        __syncthreads();

        // ---------- mfma phase ----------
        int grow = min(rt * 16 + r, N - 1);
        const u32* xrow = feat_pk + (size_t)grow * D;
        f32x4 acc = (f32x4){0.f, 0.f, 0.f, 0.f};
#pragma unroll
        for (int kt = 0; kt < 4; kt++) {
            u32 awb[8];
            *(uint4*)&awb[0] = *(const uint4*)&agg[r * 132 + kt * 32 + g * 8];
            *(uint4*)&awb[4] = *(const uint4*)&agg[r * 132 + kt * 32 + g * 8 + 4];
            bf16x8 ah, al;
            unpack8(awb, ah, al);
            u32 xwb[8];
            *(uint4*)&xwb[0] = *(const uint4*)(xrow + kt * 32 + g * 8);
            *(uint4*)&xwb[4] = *(const uint4*)(xrow + kt * 32 + g * 8 + 4);
            bf16x8 xh, xl;
            unpack8(xwb, xh, xl);
            acc = __builtin_amdgcn_mfma_f32_16x16x32_bf16(ah, Bn[kt][0], acc, 0, 0, 0);
            acc = __builtin_amdgcn_mfma_f32_16x16x32_bf16(al, Bn[kt][0], acc, 0, 0, 0);
            acc = __builtin_amdgcn_mfma_f32_16x16x32_bf16(ah, Bn[kt][1], acc, 0, 0, 0);
            acc = __builtin_amdgcn_mfma_f32_16x16x32_bf16(xh, Br[kt][0], acc, 0, 0, 0);
            acc = __builtin_amdgcn_mfma_f32_16x16x32_bf16(xl, Br[kt][0], acc, 0, 0, 0);
            acc = __builtin_amdgcn_mfma_f32_16x16x32_bf16(xh, Br[kt][1], acc, 0, 0, 0);
        }
#pragma unroll
        for (int reg = 0; reg < 4; reg++) {
            int row = rt * 16 + g * 4 + reg;  // C/D: col=lane&15, row=(lane>>4)*4+reg
            if (row >= N) continue;
            float v = acc[reg] + bv;
            if (LAYER == 0) {
                v = fmaxf(v, 0.f);
                out_pk[(size_t)row * D + wave * 16 + r] = packf(v);
            } else {
                out_f32[(size_t)row * D + wave * 16 + r] = v;
            }
        }
        __syncthreads();
    }
}

// ---------------- per-graph mean pool + FC ----------------
__global__ __launch_bounds__(128) void pool_fc_kernel(
    const float* __restrict__ h2, const int* __restrict__ gstart,
    const float* __restrict__ fcw, const float* __restrict__ fcb, float* __restrict__ out) {
    __shared__ float p[D];
    int g = blockIdx.x, t = threadIdx.x;
    int s = gstart[g], e = gstart[g + 1];
    float acc = 0.f;
    for (int r = s; r < e; r++) acc += h2[(size_t)r * D + t];
    float rc = 1.0f / fmaxf((float)(e - s), 1.0f);
    p[t] = acc * rc;
    __syncthreads();
    if (t < 10) {
        float o = fcb[t];
#pragma unroll
        for (int k = 0; k < D; k++) o += p[k] * fcw[k * 10 + t];
        out[g * 10 + t] = o;
    }
}

extern "C" void kernel_launch(void* const* d_in, const int* in_sizes, int n_in,
                              void* d_out, int out_size, void* d_ws, size_t ws_size,
                              hipStream_t stream) {
    const float* x   = (const float*)d_in[0];
    const int*   ei  = (const int*)d_in[1];
    const int* batch = (const int*)d_in[2];
    const float* w1n = (const float*)d_in[3];
    const float* b1  = (const float*)d_in[4];
    const float* w1r = (const float*)d_in[5];
    const float* w2n = (const float*)d_in[6];
    const float* b2  = (const float*)d_in[7];
    const float* w2r = (const float*)d_in[8];
    const float* fcw = (const float*)d_in[9];
    const float* fcb = (const float*)d_in[10];
    float* out = (float*)d_out;

    int N = in_sizes[0] / D;
    int E = in_sizes[1] / 2;
    const int* src = ei;
    const int* tgt = ei + E;
    int NB = (N + 255) / 256;

    // ---- workspace layout (256B-aligned regions) ----
    auto au = [](size_t v) { return (v + 255) & ~(size_t)255; };
    char* p = (char*)d_ws;
    int*   deg       = (int*)p;    p += au((size_t)N * 4);
    int*   row_start = (int*)p;    p += au((size_t)(N + 1) * 4);
    int*   partial   = (int*)p;    p += au(256 * 4);
    int*   col_idx   = (int*)p;    p += au((size_t)E * 4);
    float* rdeg      = (float*)p;  p += au((size_t)N * 4);
    int*   gstart    = (int*)p;    p += au((size_t)(G_NUM + 1) * 4);
    u16*   wp        = (u16*)p;    p += au((size_t)8 * 16384 * 2);
    u32*   xp        = (u32*)p;    p += au((size_t)N * D * 4);  // packed bf16 hi|lo of x
    u32*   h1p       = (u32*)p;    p += au((size_t)N * D * 4);  // packed h1 (post-relu)
    float* h2        = (float*)xp;  // alias: xp dead after fused<0>

    hipMemsetAsync(deg, 0, (size_t)N * 4, stream);

    // ---- fused prep: pack-x | deg | pack-w | boundary ----
    int n4 = N * 32;
    int NBX = (n4 + 255) / 256;
    int NBE = (E + 255) / 256;
    prep_kernel<<<NBX + NBE + 32 + NB, 256, 0, stream>>>(
        x, xp, w1n, w1r, w2n, w2r, wp, batch, gstart, tgt, deg, n4, E, N, NBX, NBE);

    // ---- CSR build (reused by both layers) ----
    scan1_kernel<<<NB, 256, 0, stream>>>(deg, row_start, partial, N);
    scan2_kernel<<<1, 256, 0, stream>>>(partial, NB);
    scan3_kernel<<<NB, 256, 0, stream>>>(row_start, partial, deg, rdeg, N, E);
    fill_kernel<<<NBE, 256, 0, stream>>>(src, tgt, row_start, deg, col_idx, E);

    int NT = (N + 15) / 16;
    int grid = NT < 512 ? NT : 512;

    // ---- layer 1 (gather + GEMM fused) ----
    sage_fused_kernel<0><<<grid, 512, 0, stream>>>(
        row_start, col_idx, rdeg, xp,
        wp + 0 * 32768, wp + 0 * 32768 + 16384,
        wp + 1 * 32768, wp + 1 * 32768 + 16384,
        b1, h1p, nullptr, N, NT);

    // ---- layer 2 (gather + GEMM fused) ----
    sage_fused_kernel<1><<<grid, 512, 0, stream>>>(
        row_start, col_idx, rdeg, h1p,
        wp + 2 * 32768, wp + 2 * 32768 + 16384,
        wp + 3 * 32768, wp + 3 * 32768 + 16384,
        b2, nullptr, h2, N, NT);

    // ---- pool + FC ----
    pool_fc_kernel<<<G_NUM, 128, 0, stream>>>(h2, gstart, fcw, fcb, out);
}